// Round 4
// baseline (126.275 us; speedup 1.0000x reference)
//
#include <hip/hip_runtime.h>

// Shapes fixed by the reference: B=4, N=M=384, D=256.
#define DD 256
#define NN 384
#define BB 4
#define BN (BB * NN)         // 1536
#define MSPLIT 4
#define MCHUNK (NN / MSPLIT) // 96
#define PSTRIDE (BN * DD)    // one partial plane
#define NROWS 3              // R4: 3 rows/block -> 2048 blocks = 8 blocks/CU
                             // = 8 waves/SIMD (HW max for 256-thread blocks).
                             // R2 taught: occupancy dominates; trans chains
                             // (mul->exp2->add->rcp, ~30cyc latency) need waves.

// tanh(s) = 1 - 2/(exp2(2*log2e*s)+1). K pre-scaled by 2*log2e; V pre-scaled
// by -2: per-m t2 mul eliminated, vs = -2*vsum bitwise (pow2 scale exact),
// final fmaf(-0.5, vs, acc) rounds identically. Masked rows: block-uniform
// SCALAR branch, acc += t2 (== fmaf(t2,1,acc) exactly) -> net -v. Bit-exact.
constexpr float TWO_LOG2E = 2.8853900817779268f;

// ---------------------------------------------------------------------------
// Projections. grid (BN/8, 3), block 256 = 4 waves, 8 rows/block; wave wv
// owns k in [64wv, 64wv+64), lane owns d = lane*4..+3 (float4 acc per row).
// x values are wave-uniform -> VMEM BROADCAST float4 loads from global.
// Cross-wave k-reduce through 32 KB ps at the end. (unchanged; V scale -2)
// ---------------------------------------------------------------------------
__global__ __launch_bounds__(256) void proj_kernel(
    const float* __restrict__ q,  const float* __restrict__ k,  const float* __restrict__ v,
    const float* __restrict__ Wq, const float* __restrict__ Wk, const float* __restrict__ Wv,
    const float* __restrict__ bq, const float* __restrict__ bk, const float* __restrict__ bv,
    float* __restrict__ Qout, float* __restrict__ KVout)
{
    const int tid  = threadIdx.x;
    const int lane = tid & 63;
    const int wv   = tid >> 6;          // k-slice 0..3
    const int row0 = blockIdx.x * 8;
    const int which = blockIdx.y;

    const float* X; const float* W; const float* bias; float scale; float* out; int ostride;
    if (which == 0)      { X = q; W = Wq; bias = bq; scale = 1.0f;      out = Qout;      ostride = 1; }
    else if (which == 1) { X = k; W = Wk; bias = bk; scale = TWO_LOG2E; out = KVout;     ostride = 2; }
    else                 { X = v; W = Wv; bias = bv; scale = -2.0f;     out = KVout + 1; ostride = 2; }

    __shared__ float ps[4][8][DD];      // k-slice partials, 32 KB

    const int k0 = wv * 64;
    const float* Xb = X + (size_t)row0 * DD + k0;      // x[row0+r][k0+...]
    const float* Wp = W + (size_t)k0 * DD + lane * 4;  // W[k0+...][lane*4]

    float4 acc[8];
    #pragma unroll
    for (int r = 0; r < 8; ++r) acc[r] = make_float4(0.f, 0.f, 0.f, 0.f);

    #pragma unroll 2
    for (int g = 0; g < 16; ++g) {      // 4 k's per group
        float4 xq[8];
        #pragma unroll
        for (int r = 0; r < 8; ++r)     // broadcast: all lanes same address
            xq[r] = *reinterpret_cast<const float4*>(Xb + r * DD + g * 4);
        float4 wq[4];
        #pragma unroll
        for (int u = 0; u < 4; ++u)     // coalesced 1 KB/wave
            wq[u] = *reinterpret_cast<const float4*>(Wp + (size_t)(g * 4 + u) * DD);
        #pragma unroll
        for (int u = 0; u < 4; ++u) {
            const float4 w = wq[u];
            #pragma unroll
            for (int r = 0; r < 8; ++r) {
                const float x = (u == 0) ? xq[r].x : (u == 1) ? xq[r].y
                              : (u == 2) ? xq[r].z : xq[r].w;   // resolved at compile time
                acc[r].x = fmaf(x, w.x, acc[r].x);
                acc[r].y = fmaf(x, w.y, acc[r].y);
                acc[r].z = fmaf(x, w.z, acc[r].z);
                acc[r].w = fmaf(x, w.w, acc[r].w);
            }
        }
    }

    #pragma unroll
    for (int r = 0; r < 8; ++r)
        *reinterpret_cast<float4*>(&ps[wv][r][lane * 4]) = acc[r];
    __syncthreads();

    for (int e = tid; e < 8 * DD; e += 256) {
        const int r = e >> 8;
        const int d = e & 255;
        const float s = (ps[0][r][d] + ps[1][r][d]) + (ps[2][r][d] + ps[3][r][d]);
        out[((size_t)(row0 + r) * DD + d) * ostride] = (s + bias[d]) * scale;
    }
}

// ---------------------------------------------------------------------------
// Fused tanh-contraction. grid (NN/NROWS=128, BB, MSPLIT) = 2048 blocks
// = 8 blocks/CU = 8 waves/SIMD (max). __launch_bounds__(256,8) pins VGPR<=64.
// block 256 (tid = d). NAMED float2 double-buffers; absolute-indexed loads
// (R3's walking pointer regressed: 2KB row offsets exceed the 13-bit imm and
// the pointer update added a loop-carried dep). Refills beyond m=96 overread
// harmlessly into the adjacent ws region (values unused).
// ---------------------------------------------------------------------------
__global__ __launch_bounds__(256, 8) void mhsa_kernel(
    const float* __restrict__ Q, const float* __restrict__ KV,
    const int* __restrict__ mask, float* __restrict__ outp)
{
    const int tid = threadIdx.x;         // d
    const int b   = blockIdx.y;
    const int n0  = blockIdx.x * NROWS;
    const int m0  = blockIdx.z * MCHUNK;

    __shared__ unsigned int codes[MCHUNK / 8];   // 12 words, 4-bit nibble per m
    if (tid < MCHUNK / 8) codes[tid] = 0u;
    __syncthreads();
    if (tid < MCHUNK) {                  // coalesced over m per row j
        unsigned int nib = 0u;
        #pragma unroll
        for (int j = 0; j < NROWS; ++j)
            nib |= (mask[(size_t)(b * NN + n0 + j) * NN + (m0 + tid)] ? 1u : 0u) << j;
        atomicOr(&codes[tid >> 3], nib << ((tid & 7) * 4));
    }
    __syncthreads();

    float qv0 = Q[(size_t)(b * NN + n0 + 0) * DD + tid];
    float qv1 = Q[(size_t)(b * NN + n0 + 1) * DD + tid];
    float qv2 = Q[(size_t)(b * NN + n0 + 2) * DD + tid];

    const float2* kvp = reinterpret_cast<const float2*>(KV)
                      + (size_t)b * NN * DD + (size_t)m0 * DD + tid;

    float acc0 = 0.f, acc1 = 0.f, acc2 = 0.f, vs = 0.f;

// unmasked tanh factor: t = rcp(exp2(q*k') + 1); asm pins it inside the branch
#define TANHT(QV, TT)                                                         \
    { TT = __builtin_amdgcn_rcpf(__builtin_amdgcn_exp2f((QV) * kk) + 1.0f);   \
      asm volatile("" : "+v"(TT)); }

// one m: NROWS rows; NIB is an SGPR-uniform mask (bit j = row n0+j masked).
// KVV = (k * 2log2e, -2*v). Masked row: acc += t2 (exact -2v contribution).
#define COMP(KVV, NIB)                                                        \
    {                                                                         \
        const float kk = (KVV).x;                                             \
        const float t2 = (KVV).y;                                             \
        vs += t2;                                                             \
        float t_;                                                             \
        if ((NIB) & 1u) acc0 += t2; else { TANHT(qv0, t_) acc0 = fmaf(t2, t_, acc0); } \
        if ((NIB) & 2u) acc1 += t2; else { TANHT(qv1, t_) acc1 = fmaf(t2, t_, acc1); } \
        if ((NIB) & 4u) acc2 += t2; else { TANHT(qv2, t_) acc2 = fmaf(t2, t_, acc2); } \
    }

#define LOADG(B0, B1, B2, B3, M0)                \
    B0 = kvp[(size_t)((M0) + 0) * DD];           \
    B1 = kvp[(size_t)((M0) + 1) * DD];           \
    B2 = kvp[(size_t)((M0) + 2) * DD];           \
    B3 = kvp[(size_t)((M0) + 3) * DD];

    float2 A0, A1, A2, A3, B0, B1, B2, B3;
    LOADG(A0, A1, A2, A3, 0)
    LOADG(B0, B1, B2, B3, 4)

    for (int mg = 0; mg < MCHUNK; mg += 8) {
        const unsigned int w =
            (unsigned int)__builtin_amdgcn_readfirstlane((int)codes[mg >> 3]);
        COMP(A0, (w      ) & 0xFu) COMP(A1, (w >>  4) & 0xFu)
        COMP(A2, (w >>  8) & 0xFu) COMP(A3, (w >> 12) & 0xFu)
        LOADG(A0, A1, A2, A3, mg + 8)    // mg=88 -> m 96..99: harmless overread
        COMP(B0, (w >> 16) & 0xFu) COMP(B1, (w >> 20) & 0xFu)
        COMP(B2, (w >> 24) & 0xFu) COMP(B3, (w >> 28) & 0xFu)
        LOADG(B0, B1, B2, B3, mg + 12)   // mg=88 -> m 100..103: harmless overread
    }
#undef COMP
#undef TANHT
#undef LOADG

    float* po = outp + (size_t)blockIdx.z * PSTRIDE;
    po[(size_t)(b * NN + n0 + 0) * DD + tid] = fmaf(-0.5f, vs, acc0);
    po[(size_t)(b * NN + n0 + 1) * DD + tid] = fmaf(-0.5f, vs, acc1);
    po[(size_t)(b * NN + n0 + 2) * DD + tid] = fmaf(-0.5f, vs, acc2);
}

// Sum the MSPLIT partial planes. grid BN*DD/256 = 1536 blocks.
__global__ __launch_bounds__(256) void reduce4_kernel(
    const float* __restrict__ part, float* __restrict__ out)
{
    const int i = blockIdx.x * 256 + threadIdx.x;
    out[i] = (part[i] + part[i + PSTRIDE])
           + (part[i + 2 * PSTRIDE] + part[i + 3 * PSTRIDE]);
}

extern "C" void kernel_launch(void* const* d_in, const int* in_sizes, int n_in,
                              void* d_out, int out_size, void* d_ws, size_t ws_size,
                              hipStream_t stream) {
    const float* q    = (const float*)d_in[0];
    const float* k    = (const float*)d_in[1];
    const float* v    = (const float*)d_in[2];
    const int*   mask = (const int*)  d_in[3];
    const float* Wq   = (const float*)d_in[4];
    const float* bq   = (const float*)d_in[5];
    const float* Wk   = (const float*)d_in[6];
    const float* bk   = (const float*)d_in[7];
    const float* Wv   = (const float*)d_in[8];
    const float* bv   = (const float*)d_in[9];
    float* out = (float*)d_out;

    float* Qws   = (float*)d_ws;                 // BN*DD floats      (1.57 MB)
    float* KVws  = Qws  + (size_t)BN * DD;       // BN*DD float2s     (3.15 MB)
    float* Pws   = KVws + (size_t)2 * BN * DD;   // MSPLIT planes     (6.29 MB)
                                                 // (KV overread spills into Pws: safe)

    dim3 g1(BN / 8, 3);
    proj_kernel<<<g1, 256, 0, stream>>>(q, k, v, Wq, Wk, Wv, bq, bk, bv, Qws, KVws);

    dim3 g2(NN / NROWS, BB, MSPLIT);
    mhsa_kernel<<<g2, 256, 0, stream>>>(Qws, KVws, mask, Pws);

    reduce4_kernel<<<dim3(BN * DD / 256), 256, 0, stream>>>(Pws, out);
}

// Round 6
// 124.826 us; speedup vs baseline: 1.0116x; 1.0116x over previous
//
#include <hip/hip_runtime.h>

// Shapes fixed by the reference: B=4, N=M=384, D=256.
#define DD 256
#define NN 384
#define BB 4
#define BN (BB * NN)         // 1536
#define MSPLIT 8             // R5: 8 m-chunks of 48 (was 4 x 96)
#define MCHUNK (NN / MSPLIT) // 48
#define PSTRIDE (BN * DD)    // one partial plane
#define NROWS 8              // R5: 8 n-rows/block; with MSPLIT=8 the grid stays
                             // 48*4*8 = 1536 blocks = 6 blocks/CU = 6 waves/SIMD
                             // (R2/R4 occupancy lesson: 6 w/SIMD is the optimum;
                             // R2's NROWS=8 failure was the grid shrink, not NROWS).
                             // Per-m fixed overhead instances halve vs NROWS=4.

// tanh(s) = 1 - 2/(exp2(2*log2e*s)+1). K pre-scaled by 2*log2e; V pre-scaled
// by -2: per-m t2 mul eliminated, vs = -2*vsum bitwise (pow2 scale exact),
// final fmaf(-0.5, vs, acc) rounds identically. Masked rows: block-uniform
// SCALAR branch, acc += t2 (== fmaf(t2,1,acc) exactly) -> net -v. Bit-exact.
constexpr float TWO_LOG2E = 2.8853900817779268f;

// ---------------------------------------------------------------------------
// Projections. grid (BN/8, 3), block 256 = 4 waves, 8 rows/block; wave wv
// owns k in [64wv, 64wv+64), lane owns d = lane*4..+3 (float4 acc per row).
// x values are wave-uniform -> VMEM BROADCAST float4 loads from global.
// Cross-wave k-reduce through 32 KB ps at the end. (unchanged; fp32 vector
// floor ~4-5us, FLOPs fixed — not the lever)
// ---------------------------------------------------------------------------
__global__ __launch_bounds__(256) void proj_kernel(
    const float* __restrict__ q,  const float* __restrict__ k,  const float* __restrict__ v,
    const float* __restrict__ Wq, const float* __restrict__ Wk, const float* __restrict__ Wv,
    const float* __restrict__ bq, const float* __restrict__ bk, const float* __restrict__ bv,
    float* __restrict__ Qout, float* __restrict__ KVout)
{
    const int tid  = threadIdx.x;
    const int lane = tid & 63;
    const int wv   = tid >> 6;          // k-slice 0..3
    const int row0 = blockIdx.x * 8;
    const int which = blockIdx.y;

    const float* X; const float* W; const float* bias; float scale; float* out; int ostride;
    if (which == 0)      { X = q; W = Wq; bias = bq; scale = 1.0f;      out = Qout;      ostride = 1; }
    else if (which == 1) { X = k; W = Wk; bias = bk; scale = TWO_LOG2E; out = KVout;     ostride = 2; }
    else                 { X = v; W = Wv; bias = bv; scale = -2.0f;     out = KVout + 1; ostride = 2; }

    __shared__ float ps[4][8][DD];      // k-slice partials, 32 KB

    const int k0 = wv * 64;
    const float* Xb = X + (size_t)row0 * DD + k0;      // x[row0+r][k0+...]
    const float* Wp = W + (size_t)k0 * DD + lane * 4;  // W[k0+...][lane*4]

    float4 acc[8];
    #pragma unroll
    for (int r = 0; r < 8; ++r) acc[r] = make_float4(0.f, 0.f, 0.f, 0.f);

    #pragma unroll 2
    for (int g = 0; g < 16; ++g) {      // 4 k's per group
        float4 xq[8];
        #pragma unroll
        for (int r = 0; r < 8; ++r)     // broadcast: all lanes same address
            xq[r] = *reinterpret_cast<const float4*>(Xb + r * DD + g * 4);
        float4 wq[4];
        #pragma unroll
        for (int u = 0; u < 4; ++u)     // coalesced 1 KB/wave
            wq[u] = *reinterpret_cast<const float4*>(Wp + (size_t)(g * 4 + u) * DD);
        #pragma unroll
        for (int u = 0; u < 4; ++u) {
            const float4 w = wq[u];
            #pragma unroll
            for (int r = 0; r < 8; ++r) {
                const float x = (u == 0) ? xq[r].x : (u == 1) ? xq[r].y
                              : (u == 2) ? xq[r].z : xq[r].w;   // resolved at compile time
                acc[r].x = fmaf(x, w.x, acc[r].x);
                acc[r].y = fmaf(x, w.y, acc[r].y);
                acc[r].z = fmaf(x, w.z, acc[r].z);
                acc[r].w = fmaf(x, w.w, acc[r].w);
            }
        }
    }

    #pragma unroll
    for (int r = 0; r < 8; ++r)
        *reinterpret_cast<float4*>(&ps[wv][r][lane * 4]) = acc[r];
    __syncthreads();

    for (int e = tid; e < 8 * DD; e += 256) {
        const int r = e >> 8;
        const int d = e & 255;
        const float s = (ps[0][r][d] + ps[1][r][d]) + (ps[2][r][d] + ps[3][r][d]);
        out[((size_t)(row0 + r) * DD + d) * ostride] = (s + bias[d]) * scale;
    }
}

// ---------------------------------------------------------------------------
// Fused tanh-contraction. grid (NN/NROWS=48, BB, MSPLIT=8) = 1536 blocks
// = 6 blocks/CU = 6 waves/SIMD (the measured optimum). block 256 (tid = d).
// __launch_bounds__(256,6) pins VGPR <= 85 (est. usage ~50, no spill).
// NAMED float2 double-buffers, absolute-indexed loads (R3: walking pointer
// regressed). Refills beyond m=MCHUNK overread harmlessly (next chunk /
// Pws region; values unused).
//
// Mask bits: one BYTE per m packed into 12 block-uniform words; per 8-m group
// two words go to SGPRs via readfirstlane; per (m,row) a SCALAR branch picks
// acc += t2 (masked, exact) or the exp2+rcp chain (asm-pinned).
// ---------------------------------------------------------------------------
__global__ __launch_bounds__(256, 6) void mhsa_kernel(
    const float* __restrict__ Q, const float* __restrict__ KV,
    const int* __restrict__ mask, float* __restrict__ outp)
{
    const int tid = threadIdx.x;         // d
    const int b   = blockIdx.y;
    const int n0  = blockIdx.x * NROWS;
    const int m0  = blockIdx.z * MCHUNK;

    __shared__ unsigned int codes[MCHUNK / 4];   // 12 words, one byte per m
    if (tid < MCHUNK / 4) codes[tid] = 0u;
    __syncthreads();
    if (tid < MCHUNK) {                  // coalesced over m per row j
        unsigned int by = 0u;
        #pragma unroll
        for (int j = 0; j < NROWS; ++j)
            by |= (mask[(size_t)(b * NN + n0 + j) * NN + (m0 + tid)] ? 1u : 0u) << j;
        atomicOr(&codes[tid >> 2], by << ((tid & 3) * 8));
    }
    __syncthreads();

    float qv0 = Q[(size_t)(b * NN + n0 + 0) * DD + tid];
    float qv1 = Q[(size_t)(b * NN + n0 + 1) * DD + tid];
    float qv2 = Q[(size_t)(b * NN + n0 + 2) * DD + tid];
    float qv3 = Q[(size_t)(b * NN + n0 + 3) * DD + tid];
    float qv4 = Q[(size_t)(b * NN + n0 + 4) * DD + tid];
    float qv5 = Q[(size_t)(b * NN + n0 + 5) * DD + tid];
    float qv6 = Q[(size_t)(b * NN + n0 + 6) * DD + tid];
    float qv7 = Q[(size_t)(b * NN + n0 + 7) * DD + tid];

    const float2* kvp = reinterpret_cast<const float2*>(KV)
                      + (size_t)b * NN * DD + (size_t)m0 * DD + tid;

    float acc0 = 0.f, acc1 = 0.f, acc2 = 0.f, acc3 = 0.f;
    float acc4 = 0.f, acc5 = 0.f, acc6 = 0.f, acc7 = 0.f, vs = 0.f;

// unmasked tanh factor: t = rcp(exp2(q*k') + 1); asm pins it inside the branch
#define TANHT(QV, TT)                                                         \
    { TT = __builtin_amdgcn_rcpf(__builtin_amdgcn_exp2f((QV) * kk) + 1.0f);   \
      asm volatile("" : "+v"(TT)); }

// one m: NROWS rows; MB is an SGPR-uniform byte (bit j = row n0+j masked).
// KVV = (k * 2log2e, -2*v). Masked row: acc += t2 (exact -2v contribution).
#define COMP(KVV, MB)                                                         \
    {                                                                         \
        const float kk = (KVV).x;                                             \
        const float t2 = (KVV).y;                                             \
        vs += t2;                                                             \
        float t_;                                                             \
        if ((MB) &   1u) acc0 += t2; else { TANHT(qv0, t_) acc0 = fmaf(t2, t_, acc0); } \
        if ((MB) &   2u) acc1 += t2; else { TANHT(qv1, t_) acc1 = fmaf(t2, t_, acc1); } \
        if ((MB) &   4u) acc2 += t2; else { TANHT(qv2, t_) acc2 = fmaf(t2, t_, acc2); } \
        if ((MB) &   8u) acc3 += t2; else { TANHT(qv3, t_) acc3 = fmaf(t2, t_, acc3); } \
        if ((MB) &  16u) acc4 += t2; else { TANHT(qv4, t_) acc4 = fmaf(t2, t_, acc4); } \
        if ((MB) &  32u) acc5 += t2; else { TANHT(qv5, t_) acc5 = fmaf(t2, t_, acc5); } \
        if ((MB) &  64u) acc6 += t2; else { TANHT(qv6, t_) acc6 = fmaf(t2, t_, acc6); } \
        if ((MB) & 128u) acc7 += t2; else { TANHT(qv7, t_) acc7 = fmaf(t2, t_, acc7); } \
    }

#define LOADG(B0, B1, B2, B3, M0)                \
    B0 = kvp[(size_t)((M0) + 0) * DD];           \
    B1 = kvp[(size_t)((M0) + 1) * DD];           \
    B2 = kvp[(size_t)((M0) + 2) * DD];           \
    B3 = kvp[(size_t)((M0) + 3) * DD];

    float2 A0, A1, A2, A3, B0, B1, B2, B3;
    LOADG(A0, A1, A2, A3, 0)
    LOADG(B0, B1, B2, B3, 4)

    for (int mg = 0; mg < MCHUNK; mg += 8) {
        const unsigned int w0 =
            (unsigned int)__builtin_amdgcn_readfirstlane((int)codes[(mg >> 2) + 0]);
        const unsigned int w1 =
            (unsigned int)__builtin_amdgcn_readfirstlane((int)codes[(mg >> 2) + 1]);
        COMP(A0, (w0      ) & 0xFFu) COMP(A1, (w0 >>  8) & 0xFFu)
        COMP(A2, (w0 >> 16) & 0xFFu) COMP(A3, (w0 >> 24) & 0xFFu)
        LOADG(A0, A1, A2, A3, mg + 8)    // mg=40 -> m 48..51: harmless overread
        COMP(B0, (w1      ) & 0xFFu) COMP(B1, (w1 >>  8) & 0xFFu)
        COMP(B2, (w1 >> 16) & 0xFFu) COMP(B3, (w1 >> 24) & 0xFFu)
        LOADG(B0, B1, B2, B3, mg + 12)   // mg=40 -> m 52..55: harmless overread
    }
#undef COMP
#undef TANHT
#undef LOADG

    float* po = outp + (size_t)blockIdx.z * PSTRIDE;
    po[(size_t)(b * NN + n0 + 0) * DD + tid] = fmaf(-0.5f, vs, acc0);
    po[(size_t)(b * NN + n0 + 1) * DD + tid] = fmaf(-0.5f, vs, acc1);
    po[(size_t)(b * NN + n0 + 2) * DD + tid] = fmaf(-0.5f, vs, acc2);
    po[(size_t)(b * NN + n0 + 3) * DD + tid] = fmaf(-0.5f, vs, acc3);
    po[(size_t)(b * NN + n0 + 4) * DD + tid] = fmaf(-0.5f, vs, acc4);
    po[(size_t)(b * NN + n0 + 5) * DD + tid] = fmaf(-0.5f, vs, acc5);
    po[(size_t)(b * NN + n0 + 6) * DD + tid] = fmaf(-0.5f, vs, acc6);
    po[(size_t)(b * NN + n0 + 7) * DD + tid] = fmaf(-0.5f, vs, acc7);
}

// Sum the MSPLIT=8 partial planes (pairwise tree). grid BN*DD/256 = 1536.
__global__ __launch_bounds__(256) void reduce8_kernel(
    const float* __restrict__ part, float* __restrict__ out)
{
    const int i = blockIdx.x * 256 + threadIdx.x;
    const float s01 = part[i]                + part[i + 1 * PSTRIDE];
    const float s23 = part[i + 2 * PSTRIDE] + part[i + 3 * PSTRIDE];
    const float s45 = part[i + 4 * PSTRIDE] + part[i + 5 * PSTRIDE];
    const float s67 = part[i + 6 * PSTRIDE] + part[i + 7 * PSTRIDE];
    out[i] = (s01 + s23) + (s45 + s67);
}

extern "C" void kernel_launch(void* const* d_in, const int* in_sizes, int n_in,
                              void* d_out, int out_size, void* d_ws, size_t ws_size,
                              hipStream_t stream) {
    const float* q    = (const float*)d_in[0];
    const float* k    = (const float*)d_in[1];
    const float* v    = (const float*)d_in[2];
    const int*   mask = (const int*)  d_in[3];
    const float* Wq   = (const float*)d_in[4];
    const float* bq   = (const float*)d_in[5];
    const float* Wk   = (const float*)d_in[6];
    const float* bk   = (const float*)d_in[7];
    const float* Wv   = (const float*)d_in[8];
    const float* bv   = (const float*)d_in[9];
    float* out = (float*)d_out;

    float* Qws   = (float*)d_ws;                 // BN*DD floats      (1.57 MB)
    float* KVws  = Qws  + (size_t)BN * DD;       // BN*DD float2s     (3.15 MB)
    float* Pws   = KVws + (size_t)2 * BN * DD;   // MSPLIT=8 planes   (12.6 MB)
                                                 // (KV overread spills into Pws: safe;
                                                 //  ws_size ~256MB per harness poison fill)

    dim3 g1(BN / 8, 3);
    proj_kernel<<<g1, 256, 0, stream>>>(q, k, v, Wq, Wk, Wv, bq, bk, bv, Qws, KVws);

    dim3 g2(NN / NROWS, BB, MSPLIT);
    mhsa_kernel<<<g2, 256, 0, stream>>>(Qws, KVws, mask, Pws);

    reduce8_kernel<<<dim3(BN * DD / 256), 256, 0, stream>>>(Pws, out);
}

// Round 7
// 120.788 us; speedup vs baseline: 1.0454x; 1.0334x over previous
//
#include <hip/hip_runtime.h>

// Shapes fixed by the reference: B=4, N=M=384, D=256.
#define DD 256
#define NN 384
#define BB 4
#define BN (BB * NN)         // 1536
#define MSPLIT 4
#define MCHUNK (NN / MSPLIT) // 96
#define PSTRIDE (BN * DD)    // one partial plane

// tanh(s) = 1 - 2/(exp2(2*log2e*s)+1). K pre-scaled by 2*log2e.
// Masked elements: block-uniform SCALAR branch (mask independent of d = tid):
// contribution is exactly t2*1 = -2v (+v from vsum = -v), bitwise identical
// to the exp2(-inf) path, minus 16 cycles of quarter-rate trans issue.
//
// MEASURED CONFIG OPTIMUM (R0-R6 bracket):
//   NROWS=4 x MSPLIT=4 -> 1536 blocks = 6 blocks/CU = 6 waves/SIMD: 121.6us
//   all deviations (3 or 8 w/SIMD, 8 rows, 8 m-chunks, walking ptrs,
//   issue micro-cuts) measured +1..+5us. Do not re-derive; see journal.
constexpr float TWO_LOG2E = 2.8853900817779268f;

// ---------------------------------------------------------------------------
// Projections. grid (BN/8, 3), block 256 = 4 waves, 8 rows/block; wave wv
// owns k in [64wv, 64wv+64), lane owns d = lane*4..+3 (float4 acc per row).
// x values are wave-uniform -> VMEM BROADCAST float4 loads from global.
// Cross-wave k-reduce through 32 KB ps at the end.
// ---------------------------------------------------------------------------
__global__ __launch_bounds__(256) void proj_kernel(
    const float* __restrict__ q,  const float* __restrict__ k,  const float* __restrict__ v,
    const float* __restrict__ Wq, const float* __restrict__ Wk, const float* __restrict__ Wv,
    const float* __restrict__ bq, const float* __restrict__ bk, const float* __restrict__ bv,
    float* __restrict__ Qout, float* __restrict__ KVout)
{
    const int tid  = threadIdx.x;
    const int lane = tid & 63;
    const int wv   = tid >> 6;          // k-slice 0..3
    const int row0 = blockIdx.x * 8;
    const int which = blockIdx.y;

    const float* X; const float* W; const float* bias; float scale; float* out; int ostride;
    if (which == 0)      { X = q; W = Wq; bias = bq; scale = 1.0f;      out = Qout;      ostride = 1; }
    else if (which == 1) { X = k; W = Wk; bias = bk; scale = TWO_LOG2E; out = KVout;     ostride = 2; }
    else                 { X = v; W = Wv; bias = bv; scale = 1.0f;      out = KVout + 1; ostride = 2; }

    __shared__ float ps[4][8][DD];      // k-slice partials, 32 KB

    const int k0 = wv * 64;
    const float* Xb = X + (size_t)row0 * DD + k0;      // x[row0+r][k0+...]
    const float* Wp = W + (size_t)k0 * DD + lane * 4;  // W[k0+...][lane*4]

    float4 acc[8];
    #pragma unroll
    for (int r = 0; r < 8; ++r) acc[r] = make_float4(0.f, 0.f, 0.f, 0.f);

    #pragma unroll 2
    for (int g = 0; g < 16; ++g) {      // 4 k's per group
        float4 xq[8];
        #pragma unroll
        for (int r = 0; r < 8; ++r)     // broadcast: all lanes same address
            xq[r] = *reinterpret_cast<const float4*>(Xb + r * DD + g * 4);
        float4 wq[4];
        #pragma unroll
        for (int u = 0; u < 4; ++u)     // coalesced 1 KB/wave
            wq[u] = *reinterpret_cast<const float4*>(Wp + (size_t)(g * 4 + u) * DD);
        #pragma unroll
        for (int u = 0; u < 4; ++u) {
            const float4 w = wq[u];
            #pragma unroll
            for (int r = 0; r < 8; ++r) {
                const float x = (u == 0) ? xq[r].x : (u == 1) ? xq[r].y
                              : (u == 2) ? xq[r].z : xq[r].w;   // resolved at compile time
                acc[r].x = fmaf(x, w.x, acc[r].x);
                acc[r].y = fmaf(x, w.y, acc[r].y);
                acc[r].z = fmaf(x, w.z, acc[r].z);
                acc[r].w = fmaf(x, w.w, acc[r].w);
            }
        }
    }

    #pragma unroll
    for (int r = 0; r < 8; ++r)
        *reinterpret_cast<float4*>(&ps[wv][r][lane * 4]) = acc[r];
    __syncthreads();

    for (int e = tid; e < 8 * DD; e += 256) {
        const int r = e >> 8;
        const int d = e & 255;
        const float s = (ps[0][r][d] + ps[1][r][d]) + (ps[2][r][d] + ps[3][r][d]);
        out[((size_t)(row0 + r) * DD + d) * ostride] = (s + bias[d]) * scale;
    }
}

// ---------------------------------------------------------------------------
// Fused tanh-contraction. grid (NN/4, BB, MSPLIT) = 1536 blocks (6/CU =
// 6 waves/SIMD, the measured optimum). block 256 (tid = d). NAMED float2
// double-buffers. Refills beyond m=96 overread harmlessly into the adjacent
// ws region (values unused).
//
// Mask bits packed 4-per-m into 12 block-uniform words; per mg-group of 8 m's
// one word is pulled to an SGPR via readfirstlane; per (n,m) a SCALAR branch
// (hidden under other waves' VALU) selects t=1.0 (masked, exact -v) or the
// exp2+rcp chain. asm volatile pins the chain inside the branch (no
// speculation of the quarter-rate trans ops).
// ---------------------------------------------------------------------------
__global__ __launch_bounds__(256) void mhsa_kernel(
    const float* __restrict__ Q, const float* __restrict__ KV,
    const int* __restrict__ mask, float* __restrict__ outp)
{
    const int tid = threadIdx.x;         // d
    const int b   = blockIdx.y;
    const int n0  = blockIdx.x * 4;
    const int m0  = blockIdx.z * MCHUNK;

    __shared__ unsigned int codes[MCHUNK / 8];   // 12 words, 4-bit nibble per m
    if (tid < MCHUNK / 8) codes[tid] = 0u;
    __syncthreads();
    if (tid < MCHUNK) {                  // coalesced over m per row j
        unsigned int nib = 0u;
        #pragma unroll
        for (int j = 0; j < 4; ++j)
            nib |= (mask[(size_t)(b * NN + n0 + j) * NN + (m0 + tid)] ? 1u : 0u) << j;
        atomicOr(&codes[tid >> 3], nib << ((tid & 7) * 4));
    }
    __syncthreads();

    float qv0 = Q[(size_t)(b * NN + n0 + 0) * DD + tid];
    float qv1 = Q[(size_t)(b * NN + n0 + 1) * DD + tid];
    float qv2 = Q[(size_t)(b * NN + n0 + 2) * DD + tid];
    float qv3 = Q[(size_t)(b * NN + n0 + 3) * DD + tid];

    const float2* kvp = reinterpret_cast<const float2*>(KV)
                      + (size_t)b * NN * DD + (size_t)m0 * DD + tid;

    float acc0 = 0.f, acc1 = 0.f, acc2 = 0.f, acc3 = 0.f, vsum = 0.f;

// unmasked tanh factor: t = rcp(exp2(q*k') + 1); asm pins it inside the branch
#define TANHT(QV, TT)                                                         \
    { TT = __builtin_amdgcn_rcpf(__builtin_amdgcn_exp2f((QV) * kk) + 1.0f);   \
      asm volatile("" : "+v"(TT)); }

// one m: 4 rows; NIB is an SGPR-uniform 4-bit mask (bit j = row n0+j masked)
#define COMP(KVV, NIB)                                                        \
    {                                                                         \
        const float kk = (KVV).x, vv = (KVV).y;                               \
        const float t2 = -2.0f * vv;                                          \
        vsum += vv;                                                           \
        float t_0, t_1, t_2, t_3;                                             \
        if ((NIB) & 1u) t_0 = 1.0f; else TANHT(qv0, t_0)                      \
        if ((NIB) & 2u) t_1 = 1.0f; else TANHT(qv1, t_1)                      \
        if ((NIB) & 4u) t_2 = 1.0f; else TANHT(qv2, t_2)                      \
        if ((NIB) & 8u) t_3 = 1.0f; else TANHT(qv3, t_3)                      \
        acc0 = fmaf(t2, t_0, acc0);                                           \
        acc1 = fmaf(t2, t_1, acc1);                                           \
        acc2 = fmaf(t2, t_2, acc2);                                           \
        acc3 = fmaf(t2, t_3, acc3);                                           \
    }

#define LOADG(B0, B1, B2, B3, M0)                \
    B0 = kvp[(size_t)((M0) + 0) * DD];           \
    B1 = kvp[(size_t)((M0) + 1) * DD];           \
    B2 = kvp[(size_t)((M0) + 2) * DD];           \
    B3 = kvp[(size_t)((M0) + 3) * DD];

    float2 A0, A1, A2, A3, B0, B1, B2, B3;
    LOADG(A0, A1, A2, A3, 0)
    LOADG(B0, B1, B2, B3, 4)

    for (int mg = 0; mg < MCHUNK; mg += 8) {
        const unsigned int w =
            (unsigned int)__builtin_amdgcn_readfirstlane((int)codes[mg >> 3]);
        COMP(A0, (w      ) & 0xFu) COMP(A1, (w >>  4) & 0xFu)
        COMP(A2, (w >>  8) & 0xFu) COMP(A3, (w >> 12) & 0xFu)
        LOADG(A0, A1, A2, A3, mg + 8)    // mg=88 -> m 96..99: harmless overread
        COMP(B0, (w >> 16) & 0xFu) COMP(B1, (w >> 20) & 0xFu)
        COMP(B2, (w >> 24) & 0xFu) COMP(B3, (w >> 28) & 0xFu)
        LOADG(B0, B1, B2, B3, mg + 12)   // mg=88 -> m 100..103: harmless overread
    }
#undef COMP
#undef TANHT
#undef LOADG

    float* po = outp + (size_t)blockIdx.z * PSTRIDE;
    po[(size_t)(b * NN + n0 + 0) * DD + tid] = acc0 + vsum;
    po[(size_t)(b * NN + n0 + 1) * DD + tid] = acc1 + vsum;
    po[(size_t)(b * NN + n0 + 2) * DD + tid] = acc2 + vsum;
    po[(size_t)(b * NN + n0 + 3) * DD + tid] = acc3 + vsum;
}

// Sum the MSPLIT partial planes. grid BN*DD/256 = 1536 blocks.
__global__ __launch_bounds__(256) void reduce4_kernel(
    const float* __restrict__ part, float* __restrict__ out)
{
    const int i = blockIdx.x * 256 + threadIdx.x;
    out[i] = (part[i] + part[i + PSTRIDE])
           + (part[i + 2 * PSTRIDE] + part[i + 3 * PSTRIDE]);
}

extern "C" void kernel_launch(void* const* d_in, const int* in_sizes, int n_in,
                              void* d_out, int out_size, void* d_ws, size_t ws_size,
                              hipStream_t stream) {
    const float* q    = (const float*)d_in[0];
    const float* k    = (const float*)d_in[1];
    const float* v    = (const float*)d_in[2];
    const int*   mask = (const int*)  d_in[3];
    const float* Wq   = (const float*)d_in[4];
    const float* bq   = (const float*)d_in[5];
    const float* Wk   = (const float*)d_in[6];
    const float* bk   = (const float*)d_in[7];
    const float* Wv   = (const float*)d_in[8];
    const float* bv   = (const float*)d_in[9];
    float* out = (float*)d_out;

    float* Qws   = (float*)d_ws;                 // BN*DD floats      (1.57 MB)
    float* KVws  = Qws  + (size_t)BN * DD;       // BN*DD float2s     (3.15 MB)
    float* Pws   = KVws + (size_t)2 * BN * DD;   // MSPLIT planes     (6.29 MB)
                                                 // (KV overread spills into Pws: safe)

    dim3 g1(BN / 8, 3);
    proj_kernel<<<g1, 256, 0, stream>>>(q, k, v, Wq, Wk, Wv, bq, bk, bv, Qws, KVws);

    dim3 g2(NN / 4, BB, MSPLIT);
    mhsa_kernel<<<g2, 256, 0, stream>>>(Qws, KVws, mask, Pws);

    reduce4_kernel<<<dim3(BN * DD / 256), 256, 0, stream>>>(Pws, out);
}